// Round 1
// baseline (918.810 us; speedup 1.0000x reference)
//
#include <hip/hip_runtime.h>
#include <hip/hip_bf16.h>

#define N_NODES 50000
#define N_EDGES 800000
#define N_GRAPHS 256
#define EMB 128
#define HID 256
#define NCLS 10

__device__ __forceinline__ int imax(int a, int b) { return a > b ? a : b; }

// ---------------- dtype detection ----------------
// If float inputs are bf16: every u16 of emb, viewed as bf16, is a sane small value.
// If f32: even-index u16s are mantissa garbage with random exponents -> ~half are |v|>=16/NaN.
__global__ void detect_k(const unsigned short* __restrict__ w, int* flag) {
    if (threadIdx.x == 0 && blockIdx.x == 0) {
        int ok = 1;
        for (int i = 0; i < 64; ++i) {
            float f = __uint_as_float(((unsigned)w[i]) << 16);
            if (!(fabsf(f) < 16.0f)) { ok = 0; break; }
        }
        *flag = ok;
    }
}

// ---------------- weight conversion (bf16 or f32 -> f32 in ws) ----------------
struct ConvArgs { const void* src[9]; long long cum[10]; };

__global__ void convert_k(ConvArgs a, float* __restrict__ dst, const int* __restrict__ flag) {
    int bf = *flag;
    long long total = a.cum[9];
    for (long long i = (long long)blockIdx.x * blockDim.x + threadIdx.x; i < total;
         i += (long long)gridDim.x * blockDim.x) {
        int s = 0;
        while (i >= a.cum[s + 1]) ++s;
        long long j = i - a.cum[s];
        float v;
        if (bf) v = __uint_as_float(((unsigned)((const unsigned short*)a.src[s])[j]) << 16);
        else    v = ((const float*)a.src[s])[j];
        dst[i] = v;
    }
}

__global__ void zero_k(int* __restrict__ p, int n) {
    int i = blockIdx.x * blockDim.x + threadIdx.x;
    if (i < n) p[i] = 0;
}

// ---------------- embedding gather ----------------
__global__ void embed_k(const int* __restrict__ x, const float* __restrict__ emb,
                        float* __restrict__ H0) {
    int i = blockIdx.x * blockDim.x + threadIdx.x;  // over N*32 float4 granules
    if (i >= N_NODES * 32) return;
    int n = i >> 5, q = i & 31;
    float4 v = *(const float4*)(emb + x[n] * EMB + q * 4);
    *(float4*)(H0 + (long long)n * EMB + q * 4) = v;
}

// ---------------- CSR build ----------------
__global__ void hist_edges_k(const int* __restrict__ dst, int* __restrict__ deg) {
    int e = blockIdx.x * blockDim.x + threadIdx.x;
    if (e < N_EDGES) atomicAdd(&deg[dst[e]], 1);
}
__global__ void hist_batch_k(const int* __restrict__ batch, int* __restrict__ gcnt) {
    int i = blockIdx.x * blockDim.x + threadIdx.x;
    if (i < N_NODES) atomicAdd(&gcnt[batch[i]], 1);
}

__global__ void scan_a_k(const int* __restrict__ deg, int* __restrict__ row_ptr,
                         int* __restrict__ bsum) {
    __shared__ int sm[1024];
    int gid = blockIdx.x * 1024 + threadIdx.x;
    int v = (gid < N_NODES) ? deg[gid] : 0;
    sm[threadIdx.x] = v;
    __syncthreads();
    for (int off = 1; off < 1024; off <<= 1) {
        int t = (threadIdx.x >= off) ? sm[threadIdx.x - off] : 0;
        __syncthreads();
        sm[threadIdx.x] += t;
        __syncthreads();
    }
    if (gid <= N_NODES) row_ptr[gid] = sm[threadIdx.x] - v;  // exclusive
    if (threadIdx.x == 1023) bsum[blockIdx.x] = sm[1023];
}

__global__ void scan_b_k(int* __restrict__ bsum, int nb) {
    if (threadIdx.x == 0 && blockIdx.x == 0) {
        int s = 0;
        for (int i = 0; i < nb; ++i) { int v = bsum[i]; bsum[i] = s; s += v; }
    }
}

__global__ void scan_c_k(int* __restrict__ row_ptr, const int* __restrict__ bsum,
                         int* __restrict__ nxt) {
    int gid = blockIdx.x * 1024 + threadIdx.x;
    if (gid <= N_NODES) {
        int v = row_ptr[gid] + bsum[blockIdx.x];
        row_ptr[gid] = v;
        if (gid < N_NODES) nxt[gid] = v;
    }
}

__global__ void scatter_k(const int* __restrict__ src, const int* __restrict__ dst,
                          int* __restrict__ nxt, int* __restrict__ col) {
    int e = blockIdx.x * blockDim.x + threadIdx.x;
    if (e < N_EDGES) {
        int p = atomicAdd(&nxt[dst[e]], 1);
        col[p] = src[e];
    }
}

// ---------------- CSR mean aggregation: one wave per node ----------------
template <int D>
__global__ void agg_k(const float* __restrict__ H, const int* __restrict__ row_ptr,
                      const int* __restrict__ col, float* __restrict__ M) {
    constexpr int V = D / 64;  // 2 (D=128) or 4 (D=256) floats per lane
    int w = (blockIdx.x * blockDim.x + threadIdx.x) >> 6;
    int lane = threadIdx.x & 63;
    if (w >= N_NODES) return;
    int s0 = row_ptr[w], s1 = row_ptr[w + 1];
    float acc[V] = {};
    for (int e = s0; e < s1; ++e) {
        int s = col[e];
        const float* hp = H + (long long)s * D + lane * V;
        if constexpr (V == 2) {
            float2 t = *(const float2*)hp;
            acc[0] += t.x; acc[1] += t.y;
        } else {
            float4 t = *(const float4*)hp;
            acc[0] += t.x; acc[1] += t.y; acc[2] += t.z; acc[3] += t.w;
        }
    }
    float inv = 1.0f / (float)imax(s1 - s0, 1);
    float* mp = M + (long long)w * D + lane * V;
    if constexpr (V == 2) {
        *(float2*)mp = make_float2(acc[0] * inv, acc[1] * inv);
    } else {
        *(float4*)mp = make_float4(acc[0] * inv, acc[1] * inv, acc[2] * inv, acc[3] * inv);
    }
}

// ---------------- fused two-operand GEMM: Out = relu(A1@Wl + A2@Wr + b) ----------------
// A1,A2: [N,D]; Wl,Wr: [D,HID]; Out: [N,HID]. Block: 256 threads (thread = out col),
// 32-row A tile staged in LDS; LDS reads are wave-uniform broadcasts.
template <int D>
__global__ __launch_bounds__(256, 2) void gemm_k(
    const float* __restrict__ A1, const float* __restrict__ A2,
    const float* __restrict__ Wl, const float* __restrict__ Wr,
    const float* __restrict__ bias, float* __restrict__ Out) {
    constexpr int R = 32;
    __shared__ float At[R * 2 * D];
    int tid = threadIdx.x;
    int row0 = blockIdx.x * R;
    for (int part = 0; part < 2; ++part) {
        const float* A = part ? A2 : A1;
        for (int i = tid * 4; i < R * D; i += 256 * 4) {
            int r = i / D, k = i - r * D;
            float4 v = make_float4(0.f, 0.f, 0.f, 0.f);
            if (row0 + r < N_NODES) v = *(const float4*)(A + (long long)(row0 + r) * D + k);
            *(float4*)&At[r * 2 * D + part * D + k] = v;
        }
    }
    __syncthreads();
    float acc[R];
#pragma unroll
    for (int r = 0; r < R; ++r) acc[r] = 0.f;
#pragma unroll 1
    for (int part = 0; part < 2; ++part) {
        const float* Wp = part ? Wr : Wl;
        for (int k = 0; k < D; k += 4) {
            float w0 = Wp[(k + 0) * HID + tid];
            float w1 = Wp[(k + 1) * HID + tid];
            float w2 = Wp[(k + 2) * HID + tid];
            float w3 = Wp[(k + 3) * HID + tid];
            const float* ab = &At[part * D + k];
#pragma unroll
            for (int r = 0; r < R; ++r) {
                float4 a = *(const float4*)(ab + r * 2 * D);
                acc[r] = fmaf(a.x, w0, fmaf(a.y, w1, fmaf(a.z, w2, fmaf(a.w, w3, acc[r]))));
            }
        }
    }
    float bv = bias[tid];
    for (int r = 0; r < R; ++r) {
        if (row0 + r < N_NODES) {
            float v = acc[r] + bv;
            Out[(long long)(row0 + r) * HID + tid] = v > 0.f ? v : 0.f;
        }
    }
}

// ---------------- sorted-batch graph pooling (run-length + atomics) ----------------
__global__ void pool_k(const float* __restrict__ H2, const int* __restrict__ batch,
                       float* __restrict__ g_acc) {
    int t = threadIdx.x;  // dim
    int i0 = blockIdx.x * 256;
    if (i0 >= N_NODES) return;
    int iend = i0 + 256 < N_NODES ? i0 + 256 : N_NODES;
    int cur = batch[i0];
    float run = 0.f;
    for (int i = i0; i < iend; ++i) {
        int b = batch[i];
        if (b != cur) {
            atomicAdd(&g_acc[cur * HID + t], run);
            run = 0.f;
            cur = b;
        }
        run += H2[(long long)i * HID + t];
    }
    atomicAdd(&g_acc[cur * HID + t], run);
}

// ---------------- final: out = (g_acc/cnt) @ Wo + bo ----------------
__global__ void final_k(const float* __restrict__ g_acc, const int* __restrict__ gcnt,
                        const float* __restrict__ Wo, const float* __restrict__ bo,
                        void* __restrict__ out, const int* __restrict__ flag) {
    __shared__ float gm[HID];
    __shared__ float red[HID];
    int g = blockIdx.x, t = threadIdx.x;
    float inv = 1.0f / (float)imax(gcnt[g], 1);
    gm[t] = g_acc[g * HID + t] * inv;
    __syncthreads();
    int bf = *flag;
    for (int c = 0; c < NCLS; ++c) {
        red[t] = gm[t] * Wo[t * NCLS + c];
        __syncthreads();
        for (int s = HID / 2; s > 0; s >>= 1) {
            if (t < s) red[t] += red[t + s];
            __syncthreads();
        }
        if (t == 0) {
            float o = red[0] + bo[c];
            if (bf) ((__hip_bfloat16*)out)[g * NCLS + c] = __float2bfloat16(o);
            else    ((float*)out)[g * NCLS + c] = o;
        }
        __syncthreads();
    }
}

extern "C" void kernel_launch(void* const* d_in, const int* in_sizes, int n_in,
                              void* d_out, int out_size, void* d_ws, size_t ws_size,
                              hipStream_t stream) {
    const int* x     = (const int*)d_in[0];
    const int* ei    = (const int*)d_in[1];
    const int* batch = (const int*)d_in[2];
    const int* srcp = ei;
    const int* dstp = ei + N_EDGES;

    // ---- ws layout ----
    char* w = (char*)d_ws;
    auto alloc = [&](size_t bytes) -> char* {
        char* p = w;
        w += (bytes + 255) & ~(size_t)255;
        return p;
    };
    int* flag = (int*)alloc(256);
    // contiguous zero region: deg | gcnt | g_acc
    const int ZWORDS = N_NODES + N_GRAPHS + N_GRAPHS * HID;
    int* zbase = (int*)alloc((size_t)ZWORDS * 4);
    int* deg = zbase;
    int* gcnt = zbase + N_NODES;
    float* g_acc = (float*)(zbase + N_NODES + N_GRAPHS);
    int* row_ptr = (int*)alloc((size_t)(N_NODES + 1) * 4);
    int* nxt     = (int*)alloc((size_t)N_NODES * 4);
    int* bsum    = (int*)alloc(256);
    int* col     = (int*)alloc((size_t)N_EDGES * 4);
    float* Wf    = (float*)alloc((size_t)204810 * 4);
    // M1|H0 adjacent; H2 aliases that combined region after GEMM1 consumes it.
    float* M1 = (float*)alloc((size_t)N_NODES * EMB * 4);
    float* H0 = (float*)alloc((size_t)N_NODES * EMB * 4);
    float* H2 = M1;  // alias: 50000*256 floats == M1+H0 region
    float* H1 = (float*)alloc((size_t)N_NODES * HID * 4);
    float* M2 = (float*)alloc((size_t)N_NODES * HID * 4);

    // converted weight offsets (floats)
    const long long cum[10] = {0, 5120, 37888, 70656, 70912, 136448, 201984, 202240, 204800, 204810};
    float* embW = Wf + cum[0];
    float* W1l  = Wf + cum[1];
    float* W1r  = Wf + cum[2];
    float* b1   = Wf + cum[3];
    float* W2l  = Wf + cum[4];
    float* W2r  = Wf + cum[5];
    float* b2   = Wf + cum[6];
    float* Wo   = Wf + cum[7];
    float* bo   = Wf + cum[8];

    // ---- pipeline ----
    detect_k<<<1, 64, 0, stream>>>((const unsigned short*)d_in[3], flag);

    zero_k<<<(ZWORDS + 255) / 256, 256, 0, stream>>>(zbase, ZWORDS);

    ConvArgs ca;
    for (int i = 0; i < 9; ++i) ca.src[i] = d_in[3 + i];
    for (int i = 0; i < 10; ++i) ca.cum[i] = cum[i];
    convert_k<<<801, 256, 0, stream>>>(ca, Wf, flag);

    embed_k<<<(N_NODES * 32 + 255) / 256, 256, 0, stream>>>(x, embW, H0);

    hist_edges_k<<<(N_EDGES + 255) / 256, 256, 0, stream>>>(dstp, deg);
    hist_batch_k<<<(N_NODES + 255) / 256, 256, 0, stream>>>(batch, gcnt);

    const int SBLK = (N_NODES + 1 + 1023) / 1024;  // 49
    scan_a_k<<<SBLK, 1024, 0, stream>>>(deg, row_ptr, bsum);
    scan_b_k<<<1, 64, 0, stream>>>(bsum, SBLK);
    scan_c_k<<<SBLK, 1024, 0, stream>>>(row_ptr, bsum, nxt);

    scatter_k<<<(N_EDGES + 255) / 256, 256, 0, stream>>>(srcp, dstp, nxt, col);

    // layer 1
    agg_k<EMB><<<(N_NODES * 64 + 255) / 256, 256, 0, stream>>>(H0, row_ptr, col, M1);
    gemm_k<EMB><<<(N_NODES + 31) / 32, 256, 0, stream>>>(M1, H0, W1l, W1r, b1, H1);
    // layer 2
    agg_k<HID><<<(N_NODES * 64 + 255) / 256, 256, 0, stream>>>(H1, row_ptr, col, M2);
    gemm_k<HID><<<(N_NODES + 31) / 32, 256, 0, stream>>>(M2, H1, W2l, W2r, b2, H2);

    // pooling + classifier
    pool_k<<<(N_NODES + 255) / 256, 256, 0, stream>>>(H2, batch, g_acc);
    final_k<<<N_GRAPHS, HID, 0, stream>>>(g_acc, gcnt, Wo, bo, d_out, flag);

    (void)in_sizes; (void)n_in; (void)out_size; (void)ws_size;
}

// Round 2
// 653.950 us; speedup vs baseline: 1.4050x; 1.4050x over previous
//
#include <hip/hip_runtime.h>
#include <hip/hip_bf16.h>

#define N_NODES 50000
#define N_EDGES 800000
#define N_GRAPHS 256
#define EMB 128
#define HID 256
#define NCLS 10
#define NPAD 50048  // N rounded up to 64

typedef __attribute__((ext_vector_type(4))) float f32x4;
typedef __attribute__((ext_vector_type(8))) short bf16x8;

__device__ __forceinline__ int imax(int a, int b) { return a > b ? a : b; }
__device__ __forceinline__ ushort f2bf(float f) {  // round-to-nearest-even
    unsigned u = __float_as_uint(f);
    u += 0x7fffu + ((u >> 16) & 1u);
    return (ushort)(u >> 16);
}
__device__ __forceinline__ float bf2f(ushort h) { return __uint_as_float(((unsigned)h) << 16); }

// ---------------- dtype detection (bf16 vs f32 device tensors) ----------------
__global__ void detect_k(const unsigned short* __restrict__ w, int* flag) {
    if (threadIdx.x == 0 && blockIdx.x == 0) {
        int ok = 1;
        for (int i = 0; i < 64; ++i) {
            float f = __uint_as_float(((unsigned)w[i]) << 16);
            if (!(fabsf(f) < 16.0f)) { ok = 0; break; }
        }
        *flag = ok;
    }
}

// ---------------- weight conversion (bf16 or f32 -> f32 in ws) ----------------
struct ConvArgs { const void* src[9]; long long cum[10]; };

__global__ void convert_k(ConvArgs a, float* __restrict__ dst, const int* __restrict__ flag) {
    int bf = *flag;
    long long total = a.cum[9];
    for (long long i = (long long)blockIdx.x * blockDim.x + threadIdx.x; i < total;
         i += (long long)gridDim.x * blockDim.x) {
        int s = 0;
        while (i >= a.cum[s + 1]) ++s;
        long long j = i - a.cum[s];
        float v;
        if (bf) v = bf2f(((const unsigned short*)a.src[s])[j]);
        else    v = ((const float*)a.src[s])[j];
        dst[i] = v;
    }
}

__global__ void zero_k(int* __restrict__ p, int n) {
    int i = blockIdx.x * blockDim.x + threadIdx.x;
    if (i < n) p[i] = 0;
}

// ---------------- pack W1t [256][384], W2t [256][1024] (transposed, K-duplicated) ----------------
// A1 cols: [0,128)=M1hi ->W1l, [128,256)=M1lo ->W1l, [256,384)=H0 ->W1r
// A2 cols: [0,256)=M2hi ->W2l, [256,512)=M2lo ->W2l, [512,768)=H1hi ->W2r, [768,1024)=H1lo ->W2r
__global__ void pack_w_k(const float* __restrict__ Wf, ushort* __restrict__ W1t,
                         ushort* __restrict__ W2t) {
    const int W1L = 5120, W1R = 37888, W2L = 70912, W2R = 136448;
    int i = blockIdx.x * 256 + threadIdx.x;
    if (i < 256 * 384) {
        int n = i / 384, k = i - n * 384;
        float v = (k < 256) ? Wf[W1L + (k & 127) * 256 + n] : Wf[W1R + (k - 256) * 256 + n];
        W1t[i] = f2bf(v);
    } else if (i < 256 * 384 + 256 * 1024) {
        int j = i - 256 * 384;
        int n = j / 1024, k = j - n * 1024;
        float v = (k < 512) ? Wf[W2L + (k & 255) * 256 + n] : Wf[W2R + (k & 255) * 256 + n];
        W2t[(size_t)n * 1024 + k] = f2bf(v);
    }
}

// ---------------- embedding gather -> A1 cols [256,384) as bf16 ----------------
__global__ void embed_k(const int* __restrict__ x, const float* __restrict__ emb,
                        ushort* __restrict__ A1) {
    int i = blockIdx.x * blockDim.x + threadIdx.x;
    if (i >= N_NODES * 64) return;
    int n = i >> 6, q = i & 63;
    const float2 e = *(const float2*)(emb + x[n] * EMB + q * 2);
    unsigned pk = (unsigned)f2bf(e.x) | ((unsigned)f2bf(e.y) << 16);
    *(unsigned*)(A1 + (size_t)n * 384 + 256 + q * 2) = pk;
}

// ---------------- CSR build ----------------
__global__ void hist_edges_k(const int* __restrict__ dst, int* __restrict__ deg) {
    int e = blockIdx.x * blockDim.x + threadIdx.x;
    if (e < N_EDGES) atomicAdd(&deg[dst[e]], 1);
}
__global__ void hist_batch_k(const int* __restrict__ batch, int* __restrict__ gcnt) {
    int i = blockIdx.x * blockDim.x + threadIdx.x;
    if (i < N_NODES) atomicAdd(&gcnt[batch[i]], 1);
}

__global__ void scan_a_k(const int* __restrict__ deg, int* __restrict__ row_ptr,
                         int* __restrict__ bsum) {
    __shared__ int sm[1024];
    int gid = blockIdx.x * 1024 + threadIdx.x;
    int v = (gid < N_NODES) ? deg[gid] : 0;
    sm[threadIdx.x] = v;
    __syncthreads();
    for (int off = 1; off < 1024; off <<= 1) {
        int t = (threadIdx.x >= off) ? sm[threadIdx.x - off] : 0;
        __syncthreads();
        sm[threadIdx.x] += t;
        __syncthreads();
    }
    if (gid <= N_NODES) row_ptr[gid] = sm[threadIdx.x] - v;  // exclusive
    if (threadIdx.x == 1023) bsum[blockIdx.x] = sm[1023];
}

__global__ void scan_b_k(int* __restrict__ bsum, int nb) {
    if (threadIdx.x == 0 && blockIdx.x == 0) {
        int s = 0;
        for (int i = 0; i < nb; ++i) { int v = bsum[i]; bsum[i] = s; s += v; }
    }
}

__global__ void scan_c_k(int* __restrict__ row_ptr, const int* __restrict__ bsum,
                         int* __restrict__ nxt) {
    int gid = blockIdx.x * 1024 + threadIdx.x;
    if (gid <= N_NODES) {
        int v = row_ptr[gid] + bsum[blockIdx.x];
        row_ptr[gid] = v;
        if (gid < N_NODES) nxt[gid] = v;
    }
}

__global__ void scatter_k(const int* __restrict__ src, const int* __restrict__ dst,
                          int* __restrict__ nxt, int* __restrict__ col) {
    int e = blockIdx.x * blockDim.x + threadIdx.x;
    if (e < N_EDGES) {
        int p = atomicAdd(&nxt[dst[e]], 1);
        col[p] = src[e];
    }
}

// ---------------- agg1: mean of neighbor H0 (bf16) -> M1 hi/lo into A1 cols [0,256) ----------------
__global__ void agg1_k(const int* __restrict__ row_ptr, const int* __restrict__ colv,
                       ushort* __restrict__ A1) {
    int w = (blockIdx.x * blockDim.x + threadIdx.x) >> 6;
    int lane = threadIdx.x & 63;
    if (w >= N_NODES) return;
    int s0 = row_ptr[w], s1 = row_ptr[w + 1];
    float a0 = 0.f, a1 = 0.f;
    for (int e = s0; e < s1; ++e) {
        int s = colv[e];
        unsigned v = *(const unsigned*)(A1 + (size_t)s * 384 + 256 + lane * 2);
        a0 += __uint_as_float(v << 16);
        a1 += __uint_as_float(v & 0xffff0000u);
    }
    float inv = 1.f / (float)imax(s1 - s0, 1);
    float m0 = a0 * inv, m1 = a1 * inv;
    ushort h0 = f2bf(m0), h1 = f2bf(m1);
    ushort l0 = f2bf(m0 - bf2f(h0)), l1 = f2bf(m1 - bf2f(h1));
    *(unsigned*)(A1 + (size_t)w * 384 + lane * 2)       = (unsigned)h0 | ((unsigned)h1 << 16);
    *(unsigned*)(A1 + (size_t)w * 384 + 128 + lane * 2) = (unsigned)l0 | ((unsigned)l1 << 16);
}

// ---------------- agg2: mean of neighbor H1 (hi+lo bf16) -> M2 hi/lo into A2 cols [0,512) ----------------
__global__ void agg2_k(const int* __restrict__ row_ptr, const int* __restrict__ colv,
                       ushort* __restrict__ A2) {
    int w = (blockIdx.x * blockDim.x + threadIdx.x) >> 6;
    int lane = threadIdx.x & 63;
    if (w >= N_NODES) return;
    int s0 = row_ptr[w], s1 = row_ptr[w + 1];
    float ac0 = 0.f, ac1 = 0.f, ac2 = 0.f, ac3 = 0.f;
    for (int e = s0; e < s1; ++e) {
        int s = colv[e];
        ushort4 hi = *(const ushort4*)(A2 + (size_t)s * 1024 + 512 + lane * 4);
        ushort4 lo = *(const ushort4*)(A2 + (size_t)s * 1024 + 768 + lane * 4);
        ac0 += bf2f(hi.x) + bf2f(lo.x);
        ac1 += bf2f(hi.y) + bf2f(lo.y);
        ac2 += bf2f(hi.z) + bf2f(lo.z);
        ac3 += bf2f(hi.w) + bf2f(lo.w);
    }
    float inv = 1.f / (float)imax(s1 - s0, 1);
    float m0 = ac0 * inv, m1 = ac1 * inv, m2 = ac2 * inv, m3 = ac3 * inv;
    ushort4 hs, ls;
    hs.x = f2bf(m0); ls.x = f2bf(m0 - bf2f(hs.x));
    hs.y = f2bf(m1); ls.y = f2bf(m1 - bf2f(hs.y));
    hs.z = f2bf(m2); ls.z = f2bf(m2 - bf2f(hs.z));
    hs.w = f2bf(m3); ls.w = f2bf(m3 - bf2f(hs.w));
    *(ushort4*)(A2 + (size_t)w * 1024 + lane * 4)       = hs;
    *(ushort4*)(A2 + (size_t)w * 1024 + 256 + lane * 4) = ls;
}

// ---------------- MFMA GEMM: Out = relu(A @ W + b), A:[NPAD][K] bf16, Wt:[256][K] bf16 ----------------
// Block = 4 waves; wave w -> cols [w*64, w*64+64); block -> rows [blk*64, +64).
// No LDS: A/B fragments streamed from L2/L3. k-mapping consistent across A/B (bijection-safe).
// EPI=true  (layer1): write relu as hi/lo bf16 into E cols [512,768)/[768,1024) (ldE=1024)
// EPI=false (layer2): write relu hi bf16 into out [N][256]
template <int K, bool EPI>
__global__ __launch_bounds__(256) void gemm_mfma_k(
    const ushort* __restrict__ A, const ushort* __restrict__ Wt,
    const float* __restrict__ bias, ushort* __restrict__ out, ushort* __restrict__ E) {
    int wave = threadIdx.x >> 6, lane = threadIdx.x & 63;
    int row0 = blockIdx.x * 64, col0 = wave * 64;
    const ushort* Ap = A + (size_t)(row0 + (lane & 15)) * K + ((lane >> 4) * 8);
    const ushort* Wp = Wt + (size_t)(col0 + (lane & 15)) * K + ((lane >> 4) * 8);

    f32x4 acc[4][4];
#pragma unroll
    for (int m = 0; m < 4; ++m)
#pragma unroll
        for (int n = 0; n < 4; ++n) acc[m][n] = (f32x4){0.f, 0.f, 0.f, 0.f};

    bf16x8 aA[4], bA[4], aB[4], bB[4];
#define LOADAB(kk, aa, bb)                                                         \
    {                                                                              \
        _Pragma("unroll") for (int m = 0; m < 4; ++m)                              \
            aa[m] = *(const bf16x8*)(Ap + (size_t)m * 16 * K + (kk));              \
        _Pragma("unroll") for (int n = 0; n < 4; ++n)                              \
            bb[n] = *(const bf16x8*)(Wp + (size_t)n * 16 * K + (kk));              \
    }
#define MFSTEP(aa, bb)                                                             \
    {                                                                              \
        _Pragma("unroll") for (int m = 0; m < 4; ++m)                              \
            _Pragma("unroll") for (int n = 0; n < 4; ++n)                          \
                acc[m][n] = __builtin_amdgcn_mfma_f32_16x16x32_bf16(               \
                    aa[m], bb[n], acc[m][n], 0, 0, 0);                             \
    }

    LOADAB(0, aA, bA);
#pragma unroll 1
    for (int k = 0; k < K; k += 64) {
        LOADAB(k + 32, aB, bB);
        MFSTEP(aA, bA);
        LOADAB(k + 64, aA, bA);  // last iter overreads <=64B into padded region (benign)
        MFSTEP(aB, bB);
    }

    float bv[4];
#pragma unroll
    for (int n = 0; n < 4; ++n) bv[n] = bias[col0 + n * 16 + (lane & 15)];
    int rbase = row0 + ((lane >> 4) * 4);
    int cbase = col0 + (lane & 15);
#pragma unroll
    for (int m = 0; m < 4; ++m)
#pragma unroll
        for (int n = 0; n < 4; ++n)
#pragma unroll
            for (int r = 0; r < 4; ++r) {
                int row = rbase + m * 16 + r;
                if (row < N_NODES) {
                    float v = acc[m][n][r] + bv[n];
                    v = v > 0.f ? v : 0.f;
                    int colc = cbase + n * 16;
                    if (EPI) {
                        ushort h = f2bf(v);
                        E[(size_t)row * 1024 + 512 + colc] = h;
                        E[(size_t)row * 1024 + 768 + colc] = f2bf(v - bf2f(h));
                    } else {
                        out[(size_t)row * 256 + colc] = f2bf(v);
                    }
                }
            }
#undef LOADAB
#undef MFSTEP
}

// ---------------- sorted-batch graph pooling over bf16 H2 ----------------
__global__ void pool_k(const ushort* __restrict__ H2, const int* __restrict__ batch,
                       float* __restrict__ g_acc) {
    int t = threadIdx.x;
    int i0 = blockIdx.x * 256;
    if (i0 >= N_NODES) return;
    int iend = i0 + 256 < N_NODES ? i0 + 256 : N_NODES;
    int cur = batch[i0];
    float run = 0.f;
    for (int i = i0; i < iend; ++i) {
        int b = batch[i];
        if (b != cur) {
            atomicAdd(&g_acc[cur * HID + t], run);
            run = 0.f;
            cur = b;
        }
        run += bf2f(H2[(size_t)i * HID + t]);
    }
    atomicAdd(&g_acc[cur * HID + t], run);
}

// ---------------- final: out = (g_acc/cnt) @ Wo + bo ----------------
__global__ void final_k(const float* __restrict__ g_acc, const int* __restrict__ gcnt,
                        const float* __restrict__ Wo, const float* __restrict__ bo,
                        void* __restrict__ out, const int* __restrict__ flag) {
    __shared__ float gm[HID];
    __shared__ float red[HID];
    int g = blockIdx.x, t = threadIdx.x;
    float inv = 1.0f / (float)imax(gcnt[g], 1);
    gm[t] = g_acc[g * HID + t] * inv;
    __syncthreads();
    int bf = *flag;
    for (int c = 0; c < NCLS; ++c) {
        red[t] = gm[t] * Wo[t * NCLS + c];
        __syncthreads();
        for (int s = HID / 2; s > 0; s >>= 1) {
            if (t < s) red[t] += red[t + s];
            __syncthreads();
        }
        if (t == 0) {
            float o = red[0] + bo[c];
            if (bf) ((__hip_bfloat16*)out)[g * NCLS + c] = __float2bfloat16(o);
            else    ((float*)out)[g * NCLS + c] = o;
        }
        __syncthreads();
    }
}

extern "C" void kernel_launch(void* const* d_in, const int* in_sizes, int n_in,
                              void* d_out, int out_size, void* d_ws, size_t ws_size,
                              hipStream_t stream) {
    const int* x     = (const int*)d_in[0];
    const int* ei    = (const int*)d_in[1];
    const int* batch = (const int*)d_in[2];
    const int* srcp = ei;
    const int* dstp = ei + N_EDGES;

    // ---- ws layout ----
    char* w = (char*)d_ws;
    auto alloc = [&](size_t bytes) -> char* {
        char* p = w;
        w += (bytes + 255) & ~(size_t)255;
        return p;
    };
    int* flag = (int*)alloc(256);
    const int ZWORDS = N_NODES + N_GRAPHS + N_GRAPHS * HID;  // deg | gcnt | g_acc
    int* zbase = (int*)alloc((size_t)ZWORDS * 4);
    int* deg = zbase;
    int* gcnt = zbase + N_NODES;
    float* g_acc = (float*)(zbase + N_NODES + N_GRAPHS);
    int* row_ptr = (int*)alloc((size_t)(N_NODES + 1) * 4);
    int* nxt     = (int*)alloc((size_t)N_NODES * 4);
    int* bsum    = (int*)alloc(256);
    int* col     = (int*)alloc((size_t)N_EDGES * 4);
    float* Wf    = (float*)alloc((size_t)204810 * 4);
    ushort* W1t  = (ushort*)alloc((size_t)256 * 384 * 2);
    ushort* W2t  = (ushort*)alloc((size_t)256 * 1024 * 2);
    ushort* A1   = (ushort*)alloc((size_t)NPAD * 384 * 2);   // [M1hi|M1lo|H0]
    ushort* A2   = (ushort*)alloc((size_t)NPAD * 1024 * 2);  // [M2hi|M2lo|H1hi|H1lo]
    alloc(4096);                                             // overread pad
    ushort* H2 = (ushort*)A1;  // A1 dead after gemm1; reuse for bf16 H2

    const long long cum[10] = {0, 5120, 37888, 70656, 70912, 136448, 201984, 202240, 204800, 204810};
    float* embW = Wf + cum[0];
    float* b1   = Wf + cum[3];
    float* b2   = Wf + cum[6];
    float* Wo   = Wf + cum[7];
    float* bo   = Wf + cum[8];

    // ---- pipeline ----
    detect_k<<<1, 64, 0, stream>>>((const unsigned short*)d_in[3], flag);
    zero_k<<<(ZWORDS + 255) / 256, 256, 0, stream>>>(zbase, ZWORDS);

    ConvArgs ca;
    for (int i = 0; i < 9; ++i) ca.src[i] = d_in[3 + i];
    for (int i = 0; i < 10; ++i) ca.cum[i] = cum[i];
    convert_k<<<801, 256, 0, stream>>>(ca, Wf, flag);

    pack_w_k<<<(256 * 384 + 256 * 1024 + 255) / 256, 256, 0, stream>>>(Wf, W1t, W2t);
    embed_k<<<(N_NODES * 64 + 255) / 256, 256, 0, stream>>>(x, embW, A1);

    hist_edges_k<<<(N_EDGES + 255) / 256, 256, 0, stream>>>(dstp, deg);
    hist_batch_k<<<(N_NODES + 255) / 256, 256, 0, stream>>>(batch, gcnt);

    const int SBLK = (N_NODES + 1 + 1023) / 1024;  // 49
    scan_a_k<<<SBLK, 1024, 0, stream>>>(deg, row_ptr, bsum);
    scan_b_k<<<1, 64, 0, stream>>>(bsum, SBLK);
    scan_c_k<<<SBLK, 1024, 0, stream>>>(row_ptr, bsum, nxt);
    scatter_k<<<(N_EDGES + 255) / 256, 256, 0, stream>>>(srcp, dstp, nxt, col);

    const int GB = NPAD / 64;  // 782
    // layer 1
    agg1_k<<<(N_NODES * 64 + 255) / 256, 256, 0, stream>>>(row_ptr, col, A1);
    gemm_mfma_k<384, true><<<GB, 256, 0, stream>>>(A1, W1t, b1, nullptr, A2);
    // layer 2
    agg2_k<<<(N_NODES * 64 + 255) / 256, 256, 0, stream>>>(row_ptr, col, A2);
    gemm_mfma_k<1024, false><<<GB, 256, 0, stream>>>(A2, W2t, b2, H2, nullptr);

    // pooling + classifier
    pool_k<<<(N_NODES + 255) / 256, 256, 0, stream>>>(H2, batch, g_acc);
    final_k<<<N_GRAPHS, HID, 0, stream>>>(g_acc, gcnt, Wo, bo, d_out, flag);

    (void)in_sizes; (void)n_in; (void)out_size; (void)ws_size;
}